// Round 6
// baseline (430.589 us; speedup 1.0000x reference)
//
#include <hip/hip_runtime.h>
#include <math.h>

typedef __attribute__((ext_vector_type(8))) short v8s;
typedef __attribute__((ext_vector_type(4))) float v4f;
typedef __attribute__((ext_vector_type(4))) unsigned int v4u;
typedef __attribute__((ext_vector_type(2))) unsigned int v2u;

#define MFMA16(a,b,c) __builtin_amdgcn_mfma_f32_16x16x32_bf16(a,b,c,0,0,0)
#define QSCALE 0.18033688011112042f  /* 0.125 * log2(e) */

typedef const __attribute__((address_space(1))) void* gp1_t;
typedef __attribute__((address_space(3))) void* lp3_t;
__device__ __forceinline__ void gll16(const void* g, void* l){
  __builtin_amdgcn_global_load_lds((gp1_t)g, (lp3_t)l, 16, 0, 0);
}

__device__ __forceinline__ unsigned short f2b(float f){
  unsigned u = __builtin_bit_cast(unsigned, f);
  u += 0x7FFFu + ((u>>16)&1u);
  return (unsigned short)(u>>16);
}
__device__ __forceinline__ float gelu_exact(float x){
  return 0.5f*x*(1.0f + erff(x*0.70710678118654752f));
}

// ---------------- LayerNorm (ddof=1, sd+eps) -> bf16 out ----------------
__global__ __launch_bounds__(256) void ln_kernel(const float* __restrict__ x,
    const float* __restrict__ alpha, const float* __restrict__ bias,
    unsigned short* __restrict__ out)
{
  const int D = 1024;
  int row = blockIdx.x;
  int tid = threadIdx.x;
  const float* xr = x + (size_t)row*D;
  v4f v = ((const v4f*)xr)[tid];
  float s  = v[0]+v[1]+v[2]+v[3];
  float s2 = v[0]*v[0]+v[1]*v[1]+v[2]*v[2]+v[3]*v[3];
  #pragma unroll
  for (int off=1; off<64; off<<=1){ s += __shfl_xor(s, off); s2 += __shfl_xor(s2, off); }
  __shared__ float red[8];
  int w = tid>>6;
  if ((tid&63)==0){ red[w]=s; red[4+w]=s2; }
  __syncthreads();
  s  = red[0]+red[1]+red[2]+red[3];
  s2 = red[4]+red[5]+red[6]+red[7];
  float mu  = s*(1.0f/D);
  float var = (s2 - (float)D*mu*mu)*(1.0f/(D-1));
  float inv = 1.0f/(sqrtf(fmaxf(var,0.0f)) + 1e-6f);
  v4f a  = ((const v4f*)alpha)[tid];
  v4f bi = ((const v4f*)bias)[tid];
  unsigned short o[4];
  #pragma unroll
  for (int i=0;i<4;i++) o[i] = f2b(a[i]*(v[i]-mu)*inv + bi[i]);
  v2u pk; pk[0] = (unsigned)o[0] | ((unsigned)o[1]<<16);
          pk[1] = (unsigned)o[2] | ((unsigned)o[3]<<16);
  ((v2u*)(out + (size_t)row*D))[tid] = pk;
}

// ---------------- f32 [K][N] -> bf16 [N][K] transpose ----------------
__global__ __launch_bounds__(256) void transpose_f2b(const float* __restrict__ in,
    unsigned short* __restrict__ out, int K, int N)
{
  __shared__ float t[32][33];
  int n0 = blockIdx.x*32, k0 = blockIdx.y*32;
  int tx = threadIdx.x, ty = threadIdx.y;
  #pragma unroll
  for (int j=0;j<4;j++) t[ty+8*j][tx] = in[(size_t)(k0+ty+8*j)*N + n0+tx];
  __syncthreads();
  #pragma unroll
  for (int j=0;j<4;j++) out[(size_t)(n0+ty+8*j)*K + k0+tx] = f2b(t[tx][ty+8*j]);
}

// ---------------- mask -> per-(b, 64-qtile, 64-ktile) all-ones flags --------
__global__ __launch_bounds__(256) void mask_flags(const int* __restrict__ mask,
    unsigned char* __restrict__ flags)
{
  const int S = 2048;
  int bid = blockIdx.x;            // b*1024 + qt*32 + kt
  int kt = bid & 31, qt = (bid>>5)&31, b = bid>>10;
  int tid = threadIdx.x;
  const int* mp = mask + (size_t)b*S*S + (size_t)(qt*64)*S + kt*64;
  int ok = 1;
  #pragma unroll
  for (int i=0;i<16;i++){
    int idx = tid + i*256;
    int row = idx>>6, col = idx&63;
    ok &= (mp[(size_t)row*S + col] != 0);
  }
  ok = __all(ok) ? 1 : 0;
  __shared__ int f[4];
  if ((tid&63)==0) f[tid>>6] = ok;
  __syncthreads();
  if (tid==0) flags[bid] = (unsigned char)(f[0]&f[1]&f[2]&f[3]);
}

// ---------------- bf16 V [4096][1024] -> vT [bh=32][dk=64][S=2048] ----------
__global__ __launch_bounds__(256) void v_transpose(const unsigned short* __restrict__ vB,
    unsigned short* __restrict__ vT)
{
  __shared__ unsigned short ts[64][68];
  int tt = blockIdx.x & 31, bh = blockIdx.x >> 5;
  int b = bh >> 4, h = bh & 15;
  int tid = threadIdx.x;
  int row = tid>>3, c8 = (tid&7)*8;
  const unsigned short* src = vB + ((size_t)(b*2048 + tt*64))*1024 + h*64;
  #pragma unroll
  for (int j=0;j<2;j++)
    *(v4u*)&ts[row+32*j][c8] = *(const v4u*)(src + (size_t)(row+32*j)*1024 + c8);
  __syncthreads();
  unsigned short* dst = vT + ((size_t)bh*64)*2048 + (size_t)tt*64;
  #pragma unroll
  for (int j=0;j<2;j++){
    int d = row + 32*j;
    unsigned short tmp[8];
    #pragma unroll
    for (int jj=0;jj<8;jj++) tmp[jj] = ts[c8+jj][d];
    *(v4u*)&dst[(size_t)d*2048 + c8] = *(const v4u*)tmp;
  }
}

// ---------------- fused QKV GEMM: [4096]x[1024] @ [3072][1024]^T ------------
__global__ __launch_bounds__(256) void gemm_qkv(
    const unsigned short* __restrict__ A, const unsigned short* __restrict__ Bt,
    const float* __restrict__ bq, const float* __restrict__ bk, const float* __restrict__ bv,
    unsigned short* __restrict__ qB, unsigned short* __restrict__ kB, unsigned short* __restrict__ vB)
{
  const int K = 1024, N = 1024;
  __shared__ unsigned short As[128][32];
  __shared__ unsigned short Bs[128][32];
  int m0 = blockIdx.x*128;
  int ny = blockIdx.y;              // 0..23
  int seg = ny>>3;                  // 0=q 1=k 2=v
  int n0g = ny*128;
  int tid = threadIdx.x;
  int w = tid>>6, l = tid&63;
  int wm = (w>>1)*64, wn = (w&1)*64;
  int r16 = l&15, kq = l>>4;
  v4f acc[4][4] = {};
  int t4 = tid>>2, c8 = (tid&3)*8;
  const unsigned short* Ag = A  + (size_t)(m0 + t4)*K + c8;
  const unsigned short* Bg = Bt + (size_t)(n0g + t4)*K + c8;
  char* AsB = (char*)&As[0][0] + w*1024;
  char* BsB = (char*)&Bs[0][0] + w*1024;
  for (int kb=0; kb<K; kb+=32){
    __syncthreads();
    gll16(Ag + kb,                 AsB);
    gll16(Ag + (size_t)64*K + kb,  AsB + 4096);
    gll16(Bg + kb,                 BsB);
    gll16(Bg + (size_t)64*K + kb,  BsB + 4096);
    __syncthreads();
    v8s a[4], b[4];
    #pragma unroll
    for (int mi=0;mi<4;mi++) a[mi] = *(const v8s*)&As[wm+mi*16+r16][kq*8];
    #pragma unroll
    for (int ni=0;ni<4;ni++) b[ni] = *(const v8s*)&Bs[wn+ni*16+r16][kq*8];
    #pragma unroll
    for (int mi=0;mi<4;mi++)
      #pragma unroll
      for (int ni=0;ni<4;ni++)
        acc[mi][ni] = MFMA16(a[mi], b[ni], acc[mi][ni]);
  }
  unsigned short* ob = (seg==0) ? qB : (seg==1) ? kB : vB;
  const float*    bp = (seg==0) ? bq : (seg==1) ? bk : bv;
  float sc = (seg==0) ? QSCALE : 1.0f;
  int ncol0 = (ny&7)*128;
  #pragma unroll
  for (int mi=0;mi<4;mi++){
    #pragma unroll
    for (int ni=0;ni<4;ni++){
      int col = ncol0 + wn + ni*16 + r16;
      float bvv = bp[col];
      #pragma unroll
      for (int r=0;r<4;r++){
        int row = m0 + wm + mi*16 + kq*4 + r;
        ob[(size_t)row*N + col] = f2b((acc[mi][ni][r] + bvv)*sc);
      }
    }
  }
}

// ---------------- generic GEMM: C[M][N] = A[M][K] * Bt[N][K]^T --------------
// MODE 1: outf = acc+bias+res ; MODE 2: outb = bf16(gelu(acc+bias))
// MODE 3: outf = gelu(acc+bias)+res
template<int MODE>
__global__ __launch_bounds__(256) void gemm_bt(
    const unsigned short* __restrict__ A, const unsigned short* __restrict__ Bt,
    const float* __restrict__ bias, const float* __restrict__ res,
    unsigned short* __restrict__ outb, float* __restrict__ outf,
    int M, int N, int K)
{
  __shared__ unsigned short As[128][32];
  __shared__ unsigned short Bs[128][32];
  int m0 = blockIdx.x*128, n0 = blockIdx.y*128;
  int tid = threadIdx.x;
  int w = tid>>6, l = tid&63;
  int wm = (w>>1)*64, wn = (w&1)*64;
  int r16 = l&15, kq = l>>4;
  v4f acc[4][4] = {};
  int t4 = tid>>2, c8 = (tid&3)*8;
  const unsigned short* Ag = A  + (size_t)(m0 + t4)*K + c8;
  const unsigned short* Bg = Bt + (size_t)(n0 + t4)*K + c8;
  char* AsB = (char*)&As[0][0] + w*1024;
  char* BsB = (char*)&Bs[0][0] + w*1024;
  for (int kb=0; kb<K; kb+=32){
    __syncthreads();
    gll16(Ag + kb,                 AsB);
    gll16(Ag + (size_t)64*K + kb,  AsB + 4096);
    gll16(Bg + kb,                 BsB);
    gll16(Bg + (size_t)64*K + kb,  BsB + 4096);
    __syncthreads();
    v8s a[4], b[4];
    #pragma unroll
    for (int mi=0;mi<4;mi++) a[mi] = *(const v8s*)&As[wm+mi*16+r16][kq*8];
    #pragma unroll
    for (int ni=0;ni<4;ni++) b[ni] = *(const v8s*)&Bs[wn+ni*16+r16][kq*8];
    #pragma unroll
    for (int mi=0;mi<4;mi++)
      #pragma unroll
      for (int ni=0;ni<4;ni++)
        acc[mi][ni] = MFMA16(a[mi], b[ni], acc[mi][ni]);
  }
  #pragma unroll
  for (int mi=0;mi<4;mi++){
    #pragma unroll
    for (int ni=0;ni<4;ni++){
      int col = n0 + wn + ni*16 + r16;
      float bv = bias[col];
      #pragma unroll
      for (int r=0;r<4;r++){
        int row = m0 + wm + mi*16 + kq*4 + r;
        float t = acc[mi][ni][r] + bv;
        if (MODE==2 || MODE==3) t = gelu_exact(t);
        if (MODE==2) outb[(size_t)row*N + col] = f2b(t);
        else         outf[(size_t)row*N + col] = t + res[(size_t)row*N + col];
      }
    }
  }
}

// ---------------- flash attention: barrier-free, direct-global K/V^T --------
// block = (b,h,64 q-rows) via XCD-swizzled bid; 4 waves x 16 q-rows.
__global__ __launch_bounds__(256) void attn_kernel(
    const unsigned short* __restrict__ Q, const unsigned short* __restrict__ Kb,
    const unsigned short* __restrict__ vT, const int* __restrict__ mask,
    const unsigned char* __restrict__ flags, unsigned short* __restrict__ out)
{
  const int S = 2048, D = 1024;
  __shared__ unsigned short Ps[4][16][72];   // per-wave P relayout tile
  // XCD swizzle: consecutive bid (same bh) land on the same XCD's L2
  int bid = (blockIdx.x & 7)*128 + (blockIdx.x >> 3);
  int qt = bid & 31;
  int bh = bid >> 5;
  int b = bh >> 4, h = bh & 15;
  int tid = threadIdx.x, w = tid>>6, l = tid&63;
  int r16 = l&15, kq = l>>4;
  const unsigned short* Qp  = Q  + (size_t)b*S*D + h*64;
  const unsigned short* Kp  = Kb + (size_t)b*S*D + h*64;
  const unsigned short* vTp = vT + (size_t)bh*64*S;
  int qrow0 = qt*64 + w*16;
  v8s qf[2];
  #pragma unroll
  for (int ks=0;ks<2;ks++)
    qf[ks] = *(const v8s*)(Qp + (size_t)(qrow0+r16)*D + ks*32 + kq*8);
  float m_run[4], l_run[4];
  v4f o[4] = {};
  #pragma unroll
  for (int r=0;r<4;r++){ m_run[r] = -1e30f; l_run[r] = 0.0f; }
  const int* mp = mask + (size_t)b*S*S;
  const unsigned char* fl = flags + (size_t)(b*32 + qt)*32;

  auto loadK = [&](int kt, v8s (&kf)[2][4]){
    int kt64 = kt*64;
    #pragma unroll
    for (int ks=0;ks<2;ks++)
      #pragma unroll
      for (int nj=0;nj<4;nj++)
        kf[ks][nj] = *(const v8s*)(Kp + (size_t)(kt64+nj*16+r16)*D + ks*32 + kq*8);
  };

  v8s kfb[2][2][4];
  loadK(0, kfb[0]);
  #pragma unroll 2
  for (int kt=0; kt<32; kt++){
    int kt64 = kt*64;
    v4f s[4] = {};
    // QK^T (kf loaded one iteration ahead)
    #pragma unroll
    for (int ks=0;ks<2;ks++)
      #pragma unroll
      for (int nj=0;nj<4;nj++)
        s[nj] = MFMA16(qf[ks], kfb[kt&1][ks][nj], s[nj]);
    // prefetch next K tile (covered by softmax+PV below)
    if (kt+1 < 32) loadK(kt+1, kfb[(kt+1)&1]);
    // V^T fragments for this tile (covered by softmax)
    v8s vv[2][4];
    #pragma unroll
    for (int ks=0;ks<2;ks++)
      #pragma unroll
      for (int nj=0;nj<4;nj++)
        vv[ks][nj] = *(const v8s*)(vTp + (size_t)(nj*16+r16)*S + kt64 + ks*32 + kq*8);
    // mask slow path (skipped for all-ones tiles)
    if (!fl[kt]){
      #pragma unroll
      for (int nj=0;nj<4;nj++){
        int kcol = kt64 + nj*16 + r16;
        #pragma unroll
        for (int r=0;r<4;r++){
          int qrow = qrow0 + kq*4 + r;
          if (mp[(size_t)qrow*S + kcol] == 0) s[nj][r] = -3.0e38f;
        }
      }
    }
    // online softmax in exp2 domain
    #pragma unroll
    for (int r=0;r<4;r++){
      float t = fmaxf(fmaxf(s[0][r], s[1][r]), fmaxf(s[2][r], s[3][r]));
      t = fmaxf(t, __shfl_xor(t,1));
      t = fmaxf(t, __shfl_xor(t,2));
      t = fmaxf(t, __shfl_xor(t,4));
      t = fmaxf(t, __shfl_xor(t,8));
      float mn = fmaxf(m_run[r], t);
      float corr = exp2f(m_run[r] - mn);
      m_run[r] = mn;
      float rs = 0.0f;
      #pragma unroll
      for (int nj=0;nj<4;nj++){
        float p = exp2f(s[nj][r] - mn);
        s[nj][r] = p;
        rs += p;
      }
      rs += __shfl_xor(rs,1); rs += __shfl_xor(rs,2);
      rs += __shfl_xor(rs,4); rs += __shfl_xor(rs,8);
      l_run[r] = l_run[r]*corr + rs;
      #pragma unroll
      for (int nj=0;nj<4;nj++) o[nj][r] *= corr;
    }
    // P -> per-wave LDS (no barrier needed; intra-wave lgkmcnt ordering)
    #pragma unroll
    for (int nj=0;nj<4;nj++)
      #pragma unroll
      for (int r=0;r<4;r++)
        Ps[w][kq*4+r][nj*16+r16] = f2b(s[nj][r]);
    // PV
    #pragma unroll
    for (int ks=0;ks<2;ks++){
      v8s pa = *(const v8s*)&Ps[w][r16][ks*32+kq*8];
      #pragma unroll
      for (int nj=0;nj<4;nj++)
        o[nj] = MFMA16(pa, vv[ks][nj], o[nj]);
    }
  }
  #pragma unroll
  for (int r=0;r<4;r++){
    float invl = 1.0f / l_run[r];
    int qrow = qrow0 + kq*4 + r;
    #pragma unroll
    for (int nj=0;nj<4;nj++)
      out[(size_t)(b*S+qrow)*D + h*64 + nj*16 + r16] = f2b(o[nj][r]*invl);
  }
}

// ---------------- launcher ----------------
extern "C" void kernel_launch(void* const* d_in, const int* in_sizes, int n_in,
                              void* d_out, int out_size, void* d_ws, size_t ws_size,
                              hipStream_t stream)
{
  const int D=1024, DFF=2048, BS=4096;
  const float* x      = (const float*)d_in[0];
  const int*   mask   = (const int*)d_in[1];
  const float* alpha1 = (const float*)d_in[2];
  const float* bias1  = (const float*)d_in[3];
  const float* Wq     = (const float*)d_in[4];
  const float* bq     = (const float*)d_in[5];
  const float* Wk     = (const float*)d_in[6];
  const float* bk     = (const float*)d_in[7];
  const float* Wv     = (const float*)d_in[8];
  const float* bv     = (const float*)d_in[9];
  const float* Wo     = (const float*)d_in[10];
  const float* bo     = (const float*)d_in[11];
  const float* alpha2 = (const float*)d_in[12];
  const float* bias2  = (const float*)d_in[13];
  const float* W1     = (const float*)d_in[14];
  const float* b1     = (const float*)d_in[15];
  const float* W2     = (const float*)d_in[16];
  const float* b2     = (const float*)d_in[17];
  float* outp = (float*)d_out;

  char* ws = (char*)d_ws;
  size_t off = 0;
  auto alloc = [&](size_t bytes){ void* p = ws+off; off += (bytes+255)&~(size_t)255; return p; };
  unsigned short* x2b    = (unsigned short*)alloc((size_t)BS*D*2);
  unsigned short* qB     = (unsigned short*)alloc((size_t)BS*D*2);
  unsigned short* kB     = (unsigned short*)alloc((size_t)BS*D*2);
  unsigned short* vB     = (unsigned short*)alloc((size_t)BS*D*2);
  unsigned short* attnB  = (unsigned short*)alloc((size_t)BS*D*2);
  unsigned short* h1     = (unsigned short*)alloc((size_t)BS*DFF*2);
  float*          xres   = (float*)alloc((size_t)BS*D*4);
  unsigned short* wqkvT  = (unsigned short*)alloc((size_t)3*D*D*2);
  unsigned short* woT    = (unsigned short*)alloc((size_t)D*D*2);
  unsigned short* w1T    = (unsigned short*)alloc((size_t)D*DFF*2);
  unsigned short* w2T    = (unsigned short*)alloc((size_t)DFF*D*2);
  unsigned char*  flg    = (unsigned char*)alloc(2048);
  unsigned short* vTb    = x2b;   // alias: x2b dead between gemm_qkv and ln2

  dim3 tb(32,8);
  transpose_f2b<<<dim3(D/32,  D/32 ), tb, 0, stream>>>(Wq, wqkvT,           D, D);
  transpose_f2b<<<dim3(D/32,  D/32 ), tb, 0, stream>>>(Wk, wqkvT + D*D,     D, D);
  transpose_f2b<<<dim3(D/32,  D/32 ), tb, 0, stream>>>(Wv, wqkvT + 2*D*D,   D, D);
  transpose_f2b<<<dim3(D/32,  D/32 ), tb, 0, stream>>>(Wo, woT, D, D);
  transpose_f2b<<<dim3(DFF/32,D/32 ), tb, 0, stream>>>(W1, w1T, D, DFF);
  transpose_f2b<<<dim3(D/32,  DFF/32), tb, 0, stream>>>(W2, w2T, DFF, D);

  mask_flags<<<2048, 256, 0, stream>>>(mask, flg);
  ln_kernel<<<BS, 256, 0, stream>>>(x, alpha1, bias1, x2b);

  gemm_qkv<<<dim3(BS/128, 24), 256, 0, stream>>>(x2b, wqkvT, bq, bk, bv, qB, kB, vB);

  v_transpose<<<1024, 256, 0, stream>>>(vB, vTb);

  attn_kernel<<<1024, 256, 0, stream>>>(qB, kB, vTb, mask, flg, attnB);

  gemm_bt<1><<<dim3(BS/128, D/128), 256, 0, stream>>>(attnB, woT, bo, x, nullptr, xres, BS, D, D);

  ln_kernel<<<BS, 256, 0, stream>>>(xres, alpha2, bias2, x2b);

  gemm_bt<2><<<dim3(BS/128, DFF/128), 256, 0, stream>>>(x2b, w1T, b1, nullptr, h1, nullptr, BS, DFF, D);
  gemm_bt<3><<<dim3(BS/128, D/128), 256, 0, stream>>>(h1, w2T, b2, xres, nullptr, outp, BS, D, DFF);
}

// Round 7
// 313.496 us; speedup vs baseline: 1.3735x; 1.3735x over previous
//
#include <hip/hip_runtime.h>
#include <math.h>

typedef __attribute__((ext_vector_type(8))) short v8s;
typedef __attribute__((ext_vector_type(4))) float v4f;
typedef __attribute__((ext_vector_type(4))) unsigned int v4u;
typedef __attribute__((ext_vector_type(2))) unsigned int v2u;

#define MFMA16(a,b,c) __builtin_amdgcn_mfma_f32_16x16x32_bf16(a,b,c,0,0,0)
#define QSCALE 0.18033688011112042f  /* 0.125 * log2(e) */

typedef const __attribute__((address_space(1))) void* gp1_t;
typedef __attribute__((address_space(3))) void* lp3_t;
__device__ __forceinline__ void gll16(const void* g, void* l){
  __builtin_amdgcn_global_load_lds((gp1_t)g, (lp3_t)l, 16, 0, 0);
}

__device__ __forceinline__ unsigned short f2b(float f){
  unsigned u = __builtin_bit_cast(unsigned, f);
  u += 0x7FFFu + ((u>>16)&1u);
  return (unsigned short)(u>>16);
}
__device__ __forceinline__ float gelu_exact(float x){
  return 0.5f*x*(1.0f + erff(x*0.70710678118654752f));
}

// ---------------- LayerNorm (ddof=1, sd+eps) -> bf16 out ----------------
__global__ __launch_bounds__(256) void ln_kernel(const float* __restrict__ x,
    const float* __restrict__ alpha, const float* __restrict__ bias,
    unsigned short* __restrict__ out)
{
  const int D = 1024;
  int row = blockIdx.x;
  int tid = threadIdx.x;
  const float* xr = x + (size_t)row*D;
  v4f v = ((const v4f*)xr)[tid];
  float s  = v[0]+v[1]+v[2]+v[3];
  float s2 = v[0]*v[0]+v[1]*v[1]+v[2]*v[2]+v[3]*v[3];
  #pragma unroll
  for (int off=1; off<64; off<<=1){ s += __shfl_xor(s, off); s2 += __shfl_xor(s2, off); }
  __shared__ float red[8];
  int w = tid>>6;
  if ((tid&63)==0){ red[w]=s; red[4+w]=s2; }
  __syncthreads();
  s  = red[0]+red[1]+red[2]+red[3];
  s2 = red[4]+red[5]+red[6]+red[7];
  float mu  = s*(1.0f/D);
  float var = (s2 - (float)D*mu*mu)*(1.0f/(D-1));
  float inv = 1.0f/(sqrtf(fmaxf(var,0.0f)) + 1e-6f);
  v4f a  = ((const v4f*)alpha)[tid];
  v4f bi = ((const v4f*)bias)[tid];
  unsigned short o[4];
  #pragma unroll
  for (int i=0;i<4;i++) o[i] = f2b(a[i]*(v[i]-mu)*inv + bi[i]);
  v2u pk; pk[0] = (unsigned)o[0] | ((unsigned)o[1]<<16);
          pk[1] = (unsigned)o[2] | ((unsigned)o[3]<<16);
  ((v2u*)(out + (size_t)row*D))[tid] = pk;
}

// ---------------- f32 [K][N] -> bf16 [N][K] transpose ----------------
__global__ __launch_bounds__(256) void transpose_f2b(const float* __restrict__ in,
    unsigned short* __restrict__ out, int K, int N)
{
  __shared__ float t[32][33];
  int n0 = blockIdx.x*32, k0 = blockIdx.y*32;
  int tx = threadIdx.x, ty = threadIdx.y;
  #pragma unroll
  for (int j=0;j<4;j++) t[ty+8*j][tx] = in[(size_t)(k0+ty+8*j)*N + n0+tx];
  __syncthreads();
  #pragma unroll
  for (int j=0;j<4;j++) out[(size_t)(n0+ty+8*j)*K + k0+tx] = f2b(t[tx][ty+8*j]);
}

// ---------------- mask -> per-(b, 64-qtile, 64-ktile) all-ones flags --------
__global__ __launch_bounds__(256) void mask_flags(const int* __restrict__ mask,
    unsigned char* __restrict__ flags)
{
  const int S = 2048;
  int bid = blockIdx.x;            // b*1024 + qt*32 + kt
  int kt = bid & 31, qt = (bid>>5)&31, b = bid>>10;
  int tid = threadIdx.x;
  const int* mp = mask + (size_t)b*S*S + (size_t)(qt*64)*S + kt*64;
  int ok = 1;
  #pragma unroll
  for (int i=0;i<16;i++){
    int idx = tid + i*256;
    int row = idx>>6, col = idx&63;
    ok &= (mp[(size_t)row*S + col] != 0);
  }
  ok = __all(ok) ? 1 : 0;
  __shared__ int f[4];
  if ((tid&63)==0) f[tid>>6] = ok;
  __syncthreads();
  if (tid==0) flags[bid] = (unsigned char)(f[0]&f[1]&f[2]&f[3]);
}

// ---------------- bf16 V [4096][1024] -> vT [bh=32][dk=64][S=2048] ----------
__global__ __launch_bounds__(256) void v_transpose(const unsigned short* __restrict__ vB,
    unsigned short* __restrict__ vT)
{
  __shared__ unsigned short ts[64][68];
  int tt = blockIdx.x & 31, bh = blockIdx.x >> 5;
  int b = bh >> 4, h = bh & 15;
  int tid = threadIdx.x;
  int row = tid>>3, c8 = (tid&7)*8;
  const unsigned short* src = vB + ((size_t)(b*2048 + tt*64))*1024 + h*64;
  #pragma unroll
  for (int j=0;j<2;j++)
    *(v4u*)&ts[row+32*j][c8] = *(const v4u*)(src + (size_t)(row+32*j)*1024 + c8);
  __syncthreads();
  unsigned short* dst = vT + ((size_t)bh*64)*2048 + (size_t)tt*64;
  #pragma unroll
  for (int j=0;j<2;j++){
    int d = row + 32*j;
    unsigned short tmp[8];
    #pragma unroll
    for (int jj=0;jj<8;jj++) tmp[jj] = ts[c8+jj][d];
    *(v4u*)&dst[(size_t)d*2048 + c8] = *(const v4u*)tmp;
  }
}

// ---------------- fused QKV GEMM: [4096]x[1024] @ [3072][1024]^T ------------
__global__ __launch_bounds__(256) void gemm_qkv(
    const unsigned short* __restrict__ A, const unsigned short* __restrict__ Bt,
    const float* __restrict__ bq, const float* __restrict__ bk, const float* __restrict__ bv,
    unsigned short* __restrict__ qB, unsigned short* __restrict__ kB, unsigned short* __restrict__ vB)
{
  const int K = 1024, N = 1024;
  __shared__ unsigned short As[128][32];
  __shared__ unsigned short Bs[128][32];
  int m0 = blockIdx.x*128;
  int ny = blockIdx.y;              // 0..23
  int seg = ny>>3;                  // 0=q 1=k 2=v
  int n0g = ny*128;
  int tid = threadIdx.x;
  int w = tid>>6, l = tid&63;
  int wm = (w>>1)*64, wn = (w&1)*64;
  int r16 = l&15, kq = l>>4;
  v4f acc[4][4] = {};
  int t4 = tid>>2, c8 = (tid&3)*8;
  const unsigned short* Ag = A  + (size_t)(m0 + t4)*K + c8;
  const unsigned short* Bg = Bt + (size_t)(n0g + t4)*K + c8;
  char* AsB = (char*)&As[0][0] + w*1024;
  char* BsB = (char*)&Bs[0][0] + w*1024;
  for (int kb=0; kb<K; kb+=32){
    __syncthreads();
    gll16(Ag + kb,                 AsB);
    gll16(Ag + (size_t)64*K + kb,  AsB + 4096);
    gll16(Bg + kb,                 BsB);
    gll16(Bg + (size_t)64*K + kb,  BsB + 4096);
    __syncthreads();
    v8s a[4], b[4];
    #pragma unroll
    for (int mi=0;mi<4;mi++) a[mi] = *(const v8s*)&As[wm+mi*16+r16][kq*8];
    #pragma unroll
    for (int ni=0;ni<4;ni++) b[ni] = *(const v8s*)&Bs[wn+ni*16+r16][kq*8];
    #pragma unroll
    for (int mi=0;mi<4;mi++)
      #pragma unroll
      for (int ni=0;ni<4;ni++)
        acc[mi][ni] = MFMA16(a[mi], b[ni], acc[mi][ni]);
  }
  unsigned short* ob = (seg==0) ? qB : (seg==1) ? kB : vB;
  const float*    bp = (seg==0) ? bq : (seg==1) ? bk : bv;
  float sc = (seg==0) ? QSCALE : 1.0f;
  int ncol0 = (ny&7)*128;
  #pragma unroll
  for (int mi=0;mi<4;mi++){
    #pragma unroll
    for (int ni=0;ni<4;ni++){
      int col = ncol0 + wn + ni*16 + r16;
      float bvv = bp[col];
      #pragma unroll
      for (int r=0;r<4;r++){
        int row = m0 + wm + mi*16 + kq*4 + r;
        ob[(size_t)row*N + col] = f2b((acc[mi][ni][r] + bvv)*sc);
      }
    }
  }
}

// ---------------- generic GEMM: C[M][N] = A[M][K] * Bt[N][K]^T --------------
// MODE 1: outf = acc+bias+res ; MODE 2: outb = bf16(gelu(acc+bias))
// MODE 3: outf = gelu(acc+bias)+res
template<int MODE>
__global__ __launch_bounds__(256) void gemm_bt(
    const unsigned short* __restrict__ A, const unsigned short* __restrict__ Bt,
    const float* __restrict__ bias, const float* __restrict__ res,
    unsigned short* __restrict__ outb, float* __restrict__ outf,
    int M, int N, int K)
{
  __shared__ unsigned short As[128][32];
  __shared__ unsigned short Bs[128][32];
  int m0 = blockIdx.x*128, n0 = blockIdx.y*128;
  int tid = threadIdx.x;
  int w = tid>>6, l = tid&63;
  int wm = (w>>1)*64, wn = (w&1)*64;
  int r16 = l&15, kq = l>>4;
  v4f acc[4][4] = {};
  int t4 = tid>>2, c8 = (tid&3)*8;
  const unsigned short* Ag = A  + (size_t)(m0 + t4)*K + c8;
  const unsigned short* Bg = Bt + (size_t)(n0 + t4)*K + c8;
  char* AsB = (char*)&As[0][0] + w*1024;
  char* BsB = (char*)&Bs[0][0] + w*1024;
  for (int kb=0; kb<K; kb+=32){
    __syncthreads();
    gll16(Ag + kb,                 AsB);
    gll16(Ag + (size_t)64*K + kb,  AsB + 4096);
    gll16(Bg + kb,                 BsB);
    gll16(Bg + (size_t)64*K + kb,  BsB + 4096);
    __syncthreads();
    v8s a[4], b[4];
    #pragma unroll
    for (int mi=0;mi<4;mi++) a[mi] = *(const v8s*)&As[wm+mi*16+r16][kq*8];
    #pragma unroll
    for (int ni=0;ni<4;ni++) b[ni] = *(const v8s*)&Bs[wn+ni*16+r16][kq*8];
    #pragma unroll
    for (int mi=0;mi<4;mi++)
      #pragma unroll
      for (int ni=0;ni<4;ni++)
        acc[mi][ni] = MFMA16(a[mi], b[ni], acc[mi][ni]);
  }
  #pragma unroll
  for (int mi=0;mi<4;mi++){
    #pragma unroll
    for (int ni=0;ni<4;ni++){
      int col = n0 + wn + ni*16 + r16;
      float bv = bias[col];
      #pragma unroll
      for (int r=0;r<4;r++){
        int row = m0 + wm + mi*16 + kq*4 + r;
        float t = acc[mi][ni][r] + bv;
        if (MODE==2 || MODE==3) t = gelu_exact(t);
        if (MODE==2) outb[(size_t)row*N + col] = f2b(t);
        else         outf[(size_t)row*N + col] = t + res[(size_t)row*N + col];
      }
    }
  }
}

// ---------------- flash attention: LDS-staged (gll16, swizzled), dbuf -------
// block = (b,h,64 q-rows) via XCD-swizzled bid; 4 waves x 16 q-rows.
__global__ __launch_bounds__(256, 4) void attn_kernel(
    const unsigned short* __restrict__ Q, const unsigned short* __restrict__ Kb,
    const unsigned short* __restrict__ vT, const int* __restrict__ mask,
    const unsigned char* __restrict__ flags, unsigned short* __restrict__ out)
{
  const int S = 2048, D = 1024;
  __shared__ unsigned short Kb2[2][64][64];  // 16 KB, granule-swizzled
  __shared__ unsigned short Vb2[2][64][64];  // 16 KB, granule-swizzled
  __shared__ unsigned short Ps[4][16][40];   // 5 KB, per-wave P half-tile
  int bid = (blockIdx.x & 7)*128 + (blockIdx.x >> 3);
  int qt = bid & 31;
  int bh = bid >> 5;
  int b = bh >> 4, h = bh & 15;
  int tid = threadIdx.x, w = tid>>6, l = tid&63;
  int r16 = l&15, kq = l>>4;
  const unsigned short* Qp  = Q  + (size_t)b*S*D + h*64;
  const unsigned short* Kp  = Kb + (size_t)b*S*D + h*64;
  const unsigned short* vTp = vT + (size_t)bh*64*S;
  int qrow0 = qt*64 + w*16;
  v8s qf[2];
  #pragma unroll
  for (int ks=0;ks<2;ks++)
    qf[ks] = *(const v8s*)(Qp + (size_t)(qrow0+r16)*D + ks*32 + kq*8);
  float m_run[4], l_run[4];
  v4f o[4] = {};
  #pragma unroll
  for (int r=0;r<4;r++){ m_run[r] = -1e30f; l_run[r] = 0.0f; }
  const int* mp = mask + (size_t)b*S*S;
  const unsigned char* fl = flags + (size_t)(b*32 + qt)*32;

  // staging geometry: wave w stages rows w*16..w*16+15 of both tiles.
  // lane l covers row sub*8+(l>>3), granule (l&7); source granule pre-swizzled
  // so LDS holds [row][gc ^ (row&7)] while dest stays linear (rule #21).
  int srow = l>>3;
  int gsw  = (l&7) ^ srow;       // source granule (row&7 == srow)
  auto stage = [&](int kt, int idx){
    int kt64 = kt*64;
    #pragma unroll
    for (int sub=0; sub<2; sub++){
      int row = w*16 + sub*8 + srow;
      gll16(Kp  + (size_t)(kt64+row)*D + gsw*8, &Kb2[idx][w*16+sub*8][0]);
      gll16(vTp + (size_t)row*S + kt64 + gsw*8, &Vb2[idx][w*16+sub*8][0]);
    }
  };

  stage(0, 0);
  for (int kt=0; kt<32; kt++){
    int cur = kt&1;
    __syncthreads();               // own-wave vmcnt drain => staged data visible
    if (kt+1 < 32) stage(kt+1, cur^1);   // async, covered by this iteration
    int kt64 = kt*64;
    int rx = r16 & 7;
    // QK^T from swizzled LDS
    v4f s[4] = {};
    #pragma unroll
    for (int ks=0; ks<2; ks++){
      v8s kf[4];
      #pragma unroll
      for (int nj=0; nj<4; nj++)
        kf[nj] = *(const v8s*)&Kb2[cur][nj*16+r16][((ks*4+kq)^rx)*8];
      #pragma unroll
      for (int nj=0; nj<4; nj++)
        s[nj] = MFMA16(qf[ks], kf[nj], s[nj]);
    }
    // mask slow path (skipped for all-ones tiles)
    if (!fl[kt]){
      #pragma unroll
      for (int nj=0;nj<4;nj++){
        int kcol = kt64 + nj*16 + r16;
        #pragma unroll
        for (int r=0;r<4;r++){
          int qrow = qrow0 + kq*4 + r;
          if (mp[(size_t)qrow*S + kcol] == 0) s[nj][r] = -3.0e38f;
        }
      }
    }
    // online softmax in exp2 domain
    #pragma unroll
    for (int r=0;r<4;r++){
      float t = fmaxf(fmaxf(s[0][r], s[1][r]), fmaxf(s[2][r], s[3][r]));
      t = fmaxf(t, __shfl_xor(t,1));
      t = fmaxf(t, __shfl_xor(t,2));
      t = fmaxf(t, __shfl_xor(t,4));
      t = fmaxf(t, __shfl_xor(t,8));
      float mn = fmaxf(m_run[r], t);
      float corr = exp2f(m_run[r] - mn);
      m_run[r] = mn;
      float rs = 0.0f;
      #pragma unroll
      for (int nj=0;nj<4;nj++){
        float p = exp2f(s[nj][r] - mn);
        s[nj][r] = p;
        rs += p;
      }
      rs += __shfl_xor(rs,1); rs += __shfl_xor(rs,2);
      rs += __shfl_xor(rs,4); rs += __shfl_xor(rs,8);
      l_run[r] = l_run[r]*corr + rs;
      #pragma unroll
      for (int nj=0;nj<4;nj++) o[nj][r] *= corr;
    }
    // PV in two 32-kv halves (per-wave Ps; DS pipe is in-order per wave)
    #pragma unroll
    for (int hh=0; hh<2; hh++){
      #pragma unroll
      for (int nj=hh*2; nj<hh*2+2; nj++)
        #pragma unroll
        for (int r=0;r<4;r++)
          Ps[w][kq*4+r][(nj&1)*16+r16] = f2b(s[nj][r]);
      v8s pa = *(const v8s*)&Ps[w][r16][kq*8];
      v8s vv[4];
      #pragma unroll
      for (int nj=0;nj<4;nj++)
        vv[nj] = *(const v8s*)&Vb2[cur][nj*16+r16][((hh*4+kq)^rx)*8];
      #pragma unroll
      for (int nj=0;nj<4;nj++)
        o[nj] = MFMA16(pa, vv[nj], o[nj]);
    }
  }
  #pragma unroll
  for (int r=0;r<4;r++){
    float invl = 1.0f / l_run[r];
    int qrow = qrow0 + kq*4 + r;
    #pragma unroll
    for (int nj=0;nj<4;nj++)
      out[(size_t)(b*S+qrow)*D + h*64 + nj*16 + r16] = f2b(o[nj][r]*invl);
  }
}

// ---------------- launcher ----------------
extern "C" void kernel_launch(void* const* d_in, const int* in_sizes, int n_in,
                              void* d_out, int out_size, void* d_ws, size_t ws_size,
                              hipStream_t stream)
{
  const int D=1024, DFF=2048, BS=4096;
  const float* x      = (const float*)d_in[0];
  const int*   mask   = (const int*)d_in[1];
  const float* alpha1 = (const float*)d_in[2];
  const float* bias1  = (const float*)d_in[3];
  const float* Wq     = (const float*)d_in[4];
  const float* bq     = (const float*)d_in[5];
  const float* Wk     = (const float*)d_in[6];
  const float* bk     = (const float*)d_in[7];
  const float* Wv     = (const float*)d_in[8];
  const float* bv     = (const float*)d_in[9];
  const float* Wo     = (const float*)d_in[10];
  const float* bo     = (const float*)d_in[11];
  const float* alpha2 = (const float*)d_in[12];
  const float* bias2  = (const float*)d_in[13];
  const float* W1     = (const float*)d_in[14];
  const float* b1     = (const float*)d_in[15];
  const float* W2     = (const float*)d_in[16];
  const float* b2     = (const float*)d_in[17];
  float* outp = (float*)d_out;

  char* ws = (char*)d_ws;
  size_t off = 0;
  auto alloc = [&](size_t bytes){ void* p = ws+off; off += (bytes+255)&~(size_t)255; return p; };
  unsigned short* x2b    = (unsigned short*)alloc((size_t)BS*D*2);
  unsigned short* qB     = (unsigned short*)alloc((size_t)BS*D*2);
  unsigned short* kB     = (unsigned short*)alloc((size_t)BS*D*2);
  unsigned short* vB     = (unsigned short*)alloc((size_t)BS*D*2);
  unsigned short* attnB  = (unsigned short*)alloc((size_t)BS*D*2);
  unsigned short* h1     = (unsigned short*)alloc((size_t)BS*DFF*2);
  float*          xres   = (float*)alloc((size_t)BS*D*4);
  unsigned short* wqkvT  = (unsigned short*)alloc((size_t)3*D*D*2);
  unsigned short* woT    = (unsigned short*)alloc((size_t)D*D*2);
  unsigned short* w1T    = (unsigned short*)alloc((size_t)D*DFF*2);
  unsigned short* w2T    = (unsigned short*)alloc((size_t)DFF*D*2);
  unsigned char*  flg    = (unsigned char*)alloc(2048);
  unsigned short* vTb    = x2b;   // alias: x2b dead between gemm_qkv and ln2

  dim3 tb(32,8);
  transpose_f2b<<<dim3(D/32,  D/32 ), tb, 0, stream>>>(Wq, wqkvT,           D, D);
  transpose_f2b<<<dim3(D/32,  D/32 ), tb, 0, stream>>>(Wk, wqkvT + D*D,     D, D);
  transpose_f2b<<<dim3(D/32,  D/32 ), tb, 0, stream>>>(Wv, wqkvT + 2*D*D,   D, D);
  transpose_f2b<<<dim3(D/32,  D/32 ), tb, 0, stream>>>(Wo, woT, D, D);
  transpose_f2b<<<dim3(DFF/32,D/32 ), tb, 0, stream>>>(W1, w1T, D, DFF);
  transpose_f2b<<<dim3(D/32,  DFF/32), tb, 0, stream>>>(W2, w2T, DFF, D);

  mask_flags<<<2048, 256, 0, stream>>>(mask, flg);
  ln_kernel<<<BS, 256, 0, stream>>>(x, alpha1, bias1, x2b);

  gemm_qkv<<<dim3(BS/128, 24), 256, 0, stream>>>(x2b, wqkvT, bq, bk, bv, qB, kB, vB);

  v_transpose<<<1024, 256, 0, stream>>>(vB, vTb);

  attn_kernel<<<1024, 256, 0, stream>>>(qB, kB, vTb, mask, flg, attnB);

  gemm_bt<1><<<dim3(BS/128, D/128), 256, 0, stream>>>(attnB, woT, bo, x, nullptr, xres, BS, D, D);

  ln_kernel<<<BS, 256, 0, stream>>>(xres, alpha2, bias2, x2b);

  gemm_bt<2><<<dim3(BS/128, DFF/128), 256, 0, stream>>>(x2b, w1T, b1, nullptr, h1, nullptr, BS, DFF, D);
  gemm_bt<3><<<dim3(BS/128, D/128), 256, 0, stream>>>(h1, w2T, b2, xres, nullptr, outp, BS, D, DFF);
}

// Round 8
// 272.139 us; speedup vs baseline: 1.5822x; 1.1520x over previous
//
#include <hip/hip_runtime.h>
#include <math.h>

typedef __attribute__((ext_vector_type(8))) short v8s;
typedef __attribute__((ext_vector_type(4))) float v4f;
typedef __attribute__((ext_vector_type(4))) unsigned int v4u;
typedef __attribute__((ext_vector_type(2))) unsigned int v2u;

#define MFMA16(a,b,c) __builtin_amdgcn_mfma_f32_16x16x32_bf16(a,b,c,0,0,0)
#define QSCALE 0.18033688011112042f  /* 0.125 * log2(e) */

typedef const __attribute__((address_space(1))) void* gp1_t;
typedef __attribute__((address_space(3))) void* lp3_t;
__device__ __forceinline__ void gll16(const void* g, void* l){
  __builtin_amdgcn_global_load_lds((gp1_t)g, (lp3_t)l, 16, 0, 0);
}

__device__ __forceinline__ unsigned short f2b(float f){
  unsigned u = __builtin_bit_cast(unsigned, f);
  u += 0x7FFFu + ((u>>16)&1u);
  return (unsigned short)(u>>16);
}
__device__ __forceinline__ unsigned cvtpk(float lo, float hi){
  unsigned r;
  asm("v_cvt_pk_bf16_f32 %0, %1, %2" : "=v"(r) : "v"(lo), "v"(hi));
  return r;
}
__device__ __forceinline__ float gelu_exact(float x){
  return 0.5f*x*(1.0f + erff(x*0.70710678118654752f));
}

// ---------------- LayerNorm (ddof=1, sd+eps) -> bf16 out ----------------
__global__ __launch_bounds__(256) void ln_kernel(const float* __restrict__ x,
    const float* __restrict__ alpha, const float* __restrict__ bias,
    unsigned short* __restrict__ out)
{
  const int D = 1024;
  int row = blockIdx.x;
  int tid = threadIdx.x;
  const float* xr = x + (size_t)row*D;
  v4f v = ((const v4f*)xr)[tid];
  float s  = v[0]+v[1]+v[2]+v[3];
  float s2 = v[0]*v[0]+v[1]*v[1]+v[2]*v[2]+v[3]*v[3];
  #pragma unroll
  for (int off=1; off<64; off<<=1){ s += __shfl_xor(s, off); s2 += __shfl_xor(s2, off); }
  __shared__ float red[8];
  int w = tid>>6;
  if ((tid&63)==0){ red[w]=s; red[4+w]=s2; }
  __syncthreads();
  s  = red[0]+red[1]+red[2]+red[3];
  s2 = red[4]+red[5]+red[6]+red[7];
  float mu  = s*(1.0f/D);
  float var = (s2 - (float)D*mu*mu)*(1.0f/(D-1));
  float inv = 1.0f/(sqrtf(fmaxf(var,0.0f)) + 1e-6f);
  v4f a  = ((const v4f*)alpha)[tid];
  v4f bi = ((const v4f*)bias)[tid];
  unsigned short o[4];
  #pragma unroll
  for (int i=0;i<4;i++) o[i] = f2b(a[i]*(v[i]-mu)*inv + bi[i]);
  v2u pk; pk[0] = (unsigned)o[0] | ((unsigned)o[1]<<16);
          pk[1] = (unsigned)o[2] | ((unsigned)o[3]<<16);
  ((v2u*)(out + (size_t)row*D))[tid] = pk;
}

// ---------------- f32 [K][N] -> bf16 [N][K] transpose ----------------
__global__ __launch_bounds__(256) void transpose_f2b(const float* __restrict__ in,
    unsigned short* __restrict__ out, int K, int N)
{
  __shared__ float t[32][33];
  int n0 = blockIdx.x*32, k0 = blockIdx.y*32;
  int tx = threadIdx.x, ty = threadIdx.y;
  #pragma unroll
  for (int j=0;j<4;j++) t[ty+8*j][tx] = in[(size_t)(k0+ty+8*j)*N + n0+tx];
  __syncthreads();
  #pragma unroll
  for (int j=0;j<4;j++) out[(size_t)(n0+ty+8*j)*K + k0+tx] = f2b(t[tx][ty+8*j]);
}

// ---------------- mask -> per-(b, 64-qtile, 64-ktile) all-ones flags --------
__global__ __launch_bounds__(256) void mask_flags(const int* __restrict__ mask,
    unsigned char* __restrict__ flags)
{
  const int S = 2048;
  int bid = blockIdx.x;            // b*1024 + qt*32 + kt
  int kt = bid & 31, qt = (bid>>5)&31, b = bid>>10;
  int tid = threadIdx.x;
  const int* mp = mask + (size_t)b*S*S + (size_t)(qt*64)*S + kt*64;
  int ok = 1;
  #pragma unroll
  for (int i=0;i<16;i++){
    int idx = tid + i*256;
    int row = idx>>6, col = idx&63;
    ok &= (mp[(size_t)row*S + col] != 0);
  }
  ok = __all(ok) ? 1 : 0;
  __shared__ int f[4];
  if ((tid&63)==0) f[tid>>6] = ok;
  __syncthreads();
  if (tid==0) flags[bid] = (unsigned char)(f[0]&f[1]&f[2]&f[3]);
}

// ---------------- bf16 V [4096][1024] -> vT [bh=32][dk=64][S=2048] ----------
__global__ __launch_bounds__(256) void v_transpose(const unsigned short* __restrict__ vB,
    unsigned short* __restrict__ vT)
{
  __shared__ unsigned short ts[64][68];
  int tt = blockIdx.x & 31, bh = blockIdx.x >> 5;
  int b = bh >> 4, h = bh & 15;
  int tid = threadIdx.x;
  int row = tid>>3, c8 = (tid&7)*8;
  const unsigned short* src = vB + ((size_t)(b*2048 + tt*64))*1024 + h*64;
  #pragma unroll
  for (int j=0;j<2;j++)
    *(v4u*)&ts[row+32*j][c8] = *(const v4u*)(src + (size_t)(row+32*j)*1024 + c8);
  __syncthreads();
  unsigned short* dst = vT + ((size_t)bh*64)*2048 + (size_t)tt*64;
  #pragma unroll
  for (int j=0;j<2;j++){
    int d = row + 32*j;
    unsigned short tmp[8];
    #pragma unroll
    for (int jj=0;jj<8;jj++) tmp[jj] = ts[c8+jj][d];
    *(v4u*)&dst[(size_t)d*2048 + c8] = *(const v4u*)tmp;
  }
}

// ---------------- fused QKV GEMM (dbuf LDS): [4096]x[1024] @ [3072][1024]^T -
__global__ __launch_bounds__(256) void gemm_qkv(
    const unsigned short* __restrict__ A, const unsigned short* __restrict__ Bt,
    const float* __restrict__ bq, const float* __restrict__ bk, const float* __restrict__ bv,
    unsigned short* __restrict__ qB, unsigned short* __restrict__ kB, unsigned short* __restrict__ vB)
{
  const int K = 1024, N = 1024;
  __shared__ unsigned short As[2][128][32];
  __shared__ unsigned short Bs[2][128][32];
  int m0 = blockIdx.x*128;
  int ny = blockIdx.y;              // 0..23
  int seg = ny>>3;                  // 0=q 1=k 2=v
  int n0g = ny*128;
  int tid = threadIdx.x;
  int w = tid>>6, l = tid&63;
  int wm = (w>>1)*64, wn = (w&1)*64;
  int r16 = l&15, kq = l>>4;
  v4f acc[4][4] = {};
  int t4 = tid>>2, c8 = (tid&3)*8;
  const unsigned short* Ag = A  + (size_t)(m0 + t4)*K + c8;
  const unsigned short* Bg = Bt + (size_t)(n0g + t4)*K + c8;
  auto stageG = [&](int kb, int idx){
    char* a = (char*)&As[idx][0][0] + w*1024;
    char* b = (char*)&Bs[idx][0][0] + w*1024;
    gll16(Ag + kb,                a);
    gll16(Ag + (size_t)64*K + kb, a + 4096);
    gll16(Bg + kb,                b);
    gll16(Bg + (size_t)64*K + kb, b + 4096);
  };
  stageG(0, 0);
  for (int i=0; i<K/32; i++){
    int cur = i&1;
    __syncthreads();                       // drains vmcnt -> buf[cur] ready
    if (i+1 < K/32) stageG((i+1)*32, cur^1);
    v8s a[4], b[4];
    #pragma unroll
    for (int mi=0;mi<4;mi++) a[mi] = *(const v8s*)&As[cur][wm+mi*16+r16][kq*8];
    #pragma unroll
    for (int ni=0;ni<4;ni++) b[ni] = *(const v8s*)&Bs[cur][wn+ni*16+r16][kq*8];
    #pragma unroll
    for (int mi=0;mi<4;mi++)
      #pragma unroll
      for (int ni=0;ni<4;ni++)
        acc[mi][ni] = MFMA16(a[mi], b[ni], acc[mi][ni]);
  }
  unsigned short* ob = (seg==0) ? qB : (seg==1) ? kB : vB;
  const float*    bp = (seg==0) ? bq : (seg==1) ? bk : bv;
  float sc = (seg==0) ? QSCALE : 1.0f;
  int ncol0 = (ny&7)*128;
  #pragma unroll
  for (int mi=0;mi<4;mi++){
    #pragma unroll
    for (int ni=0;ni<4;ni++){
      int col = ncol0 + wn + ni*16 + r16;
      float bvv = bp[col];
      #pragma unroll
      for (int r=0;r<4;r++){
        int row = m0 + wm + mi*16 + kq*4 + r;
        ob[(size_t)row*N + col] = f2b((acc[mi][ni][r] + bvv)*sc);
      }
    }
  }
}

// ---------------- generic GEMM (dbuf LDS): C[M][N] = A[M][K] * Bt[N][K]^T ---
// MODE 1: outf = acc+bias+res ; MODE 2: outb = bf16(gelu(acc+bias))
// MODE 3: outf = gelu(acc+bias)+res
template<int MODE>
__global__ __launch_bounds__(256) void gemm_bt(
    const unsigned short* __restrict__ A, const unsigned short* __restrict__ Bt,
    const float* __restrict__ bias, const float* __restrict__ res,
    unsigned short* __restrict__ outb, float* __restrict__ outf,
    int M, int N, int K)
{
  __shared__ unsigned short As[2][128][32];
  __shared__ unsigned short Bs[2][128][32];
  int m0 = blockIdx.x*128, n0 = blockIdx.y*128;
  int tid = threadIdx.x;
  int w = tid>>6, l = tid&63;
  int wm = (w>>1)*64, wn = (w&1)*64;
  int r16 = l&15, kq = l>>4;
  v4f acc[4][4] = {};
  int t4 = tid>>2, c8 = (tid&3)*8;
  const unsigned short* Ag = A  + (size_t)(m0 + t4)*K + c8;
  const unsigned short* Bg = Bt + (size_t)(n0 + t4)*K + c8;
  auto stageG = [&](int kb, int idx){
    char* a = (char*)&As[idx][0][0] + w*1024;
    char* b = (char*)&Bs[idx][0][0] + w*1024;
    gll16(Ag + kb,                a);
    gll16(Ag + (size_t)64*K + kb, a + 4096);
    gll16(Bg + kb,                b);
    gll16(Bg + (size_t)64*K + kb, b + 4096);
  };
  stageG(0, 0);
  int nk = K/32;
  for (int i=0; i<nk; i++){
    int cur = i&1;
    __syncthreads();
    if (i+1 < nk) stageG((i+1)*32, cur^1);
    v8s a[4], b[4];
    #pragma unroll
    for (int mi=0;mi<4;mi++) a[mi] = *(const v8s*)&As[cur][wm+mi*16+r16][kq*8];
    #pragma unroll
    for (int ni=0;ni<4;ni++) b[ni] = *(const v8s*)&Bs[cur][wn+ni*16+r16][kq*8];
    #pragma unroll
    for (int mi=0;mi<4;mi++)
      #pragma unroll
      for (int ni=0;ni<4;ni++)
        acc[mi][ni] = MFMA16(a[mi], b[ni], acc[mi][ni]);
  }
  #pragma unroll
  for (int mi=0;mi<4;mi++){
    #pragma unroll
    for (int ni=0;ni<4;ni++){
      int col = n0 + wn + ni*16 + r16;
      float bv = bias[col];
      #pragma unroll
      for (int r=0;r<4;r++){
        int row = m0 + wm + mi*16 + kq*4 + r;
        float t = acc[mi][ni][r] + bv;
        if (MODE==2 || MODE==3) t = gelu_exact(t);
        if (MODE==2) outb[(size_t)row*N + col] = f2b(t);
        else         outf[(size_t)row*N + col] = t + res[(size_t)row*N + col];
      }
    }
  }
}

// ---------------- flash attention: swapped QK^T, lane-local softmax ---------
// block = (b,h,64 q-rows) XCD-swizzled; 4 waves x 16 q-rows; LDS dbuf staging.
__global__ __launch_bounds__(256, 4) void attn_kernel(
    const unsigned short* __restrict__ Q, const unsigned short* __restrict__ Kb,
    const unsigned short* __restrict__ vT, const int* __restrict__ mask,
    const unsigned char* __restrict__ flags, unsigned short* __restrict__ out)
{
  const int S = 2048, D = 1024;
  __shared__ unsigned short Kb2[2][64][64];  // 16 KB, granule-swizzled
  __shared__ unsigned short Vb2[2][64][64];  // 16 KB, granule-swizzled
  __shared__ unsigned short Ps[4][16][36];   // 4.5 KB, per-wave P^T half-tile
  int bid = (blockIdx.x & 7)*128 + (blockIdx.x >> 3);
  int qt = bid & 31;
  int bh = bid >> 5;
  int b = bh >> 4, h = bh & 15;
  int tid = threadIdx.x, w = tid>>6, l = tid&63;
  int r16 = l&15, kq = l>>4;
  const unsigned short* Qp  = Q  + (size_t)b*S*D + h*64;
  const unsigned short* Kp  = Kb + (size_t)b*S*D + h*64;
  const unsigned short* vTp = vT + (size_t)bh*64*S;
  int qrow0 = qt*64 + w*16;
  v8s qf[2];
  #pragma unroll
  for (int ks=0;ks<2;ks++)
    qf[ks] = *(const v8s*)(Qp + (size_t)(qrow0+r16)*D + ks*32 + kq*8);
  // lane-local softmax state for q = qrow0 + r16
  float m_run = -1e30f, l_run = 0.0f;
  v4f o[4] = {};   // o[nj][r]: O[q=qrow0+r16][d = nj*16 + kq*4 + r]
  const int* mp = mask + (size_t)b*S*S;
  const unsigned char* fl = flags + (size_t)(b*32 + qt)*32;

  int srow = l>>3;
  int gsw  = (l&7) ^ srow;       // pre-swizzled source granule (rule #21)
  auto stage = [&](int kt, int idx){
    int kt64 = kt*64;
    #pragma unroll
    for (int sub=0; sub<2; sub++){
      int row = w*16 + sub*8 + srow;
      gll16(Kp  + (size_t)(kt64+row)*D + gsw*8, &Kb2[idx][w*16+sub*8][0]);
      gll16(vTp + (size_t)row*S + kt64 + gsw*8, &Vb2[idx][w*16+sub*8][0]);
    }
  };

  stage(0, 0);
  for (int kt=0; kt<32; kt++){
    int cur = kt&1;
    __syncthreads();               // vmcnt drain => staged data visible
    if (kt+1 < 32) stage(kt+1, cur^1);
    int kt64 = kt*64;
    int rx = r16 & 7;
    // swapped QK^T: s[nj][r] = P^T[kv = kt64+nj*16+kq*4+r][q = r16]
    v4f s[4] = {};
    #pragma unroll
    for (int ks=0; ks<2; ks++){
      v8s kf[4];
      #pragma unroll
      for (int nj=0; nj<4; nj++)
        kf[nj] = *(const v8s*)&Kb2[cur][nj*16+r16][((ks*4+kq)^rx)*8];
      #pragma unroll
      for (int nj=0; nj<4; nj++)
        s[nj] = MFMA16(kf[nj], qf[ks], s[nj]);   // A=K, B=Q
    }
    // mask slow path (skipped for all-ones tiles)
    if (!fl[kt]){
      int qrow = qrow0 + r16;
      #pragma unroll
      for (int nj=0;nj<4;nj++){
        #pragma unroll
        for (int r=0;r<4;r++){
          int kcol = kt64 + nj*16 + kq*4 + r;
          if (mp[(size_t)qrow*S + kcol] == 0) s[nj][r] = -3.0e38f;
        }
      }
    }
    // lane-local online softmax (exp2 domain), defer-max
    float t0 = fmaxf(fmaxf(s[0][0],s[0][1]), fmaxf(s[0][2],s[0][3]));
    float t1 = fmaxf(fmaxf(s[1][0],s[1][1]), fmaxf(s[1][2],s[1][3]));
    float t2 = fmaxf(fmaxf(s[2][0],s[2][1]), fmaxf(s[2][2],s[2][3]));
    float t3 = fmaxf(fmaxf(s[3][0],s[3][1]), fmaxf(s[3][2],s[3][3]));
    float tm = fmaxf(fmaxf(t0,t1), fmaxf(t2,t3));
    tm = fmaxf(tm, __shfl_xor(tm,16));
    tm = fmaxf(tm, __shfl_xor(tm,32));
    if (!__all(tm <= m_run + 11.5f)){      // rescale needed somewhere in wave
      float mn = fmaxf(m_run, tm);
      float corr = exp2f(m_run - mn);
      m_run = mn;
      l_run *= corr;
      #pragma unroll
      for (int nj=0;nj<4;nj++)
        #pragma unroll
        for (int r=0;r<4;r++) o[nj][r] *= corr;
    }
    #pragma unroll
    for (int nj=0;nj<4;nj++)
      #pragma unroll
      for (int r=0;r<4;r++)
        s[nj][r] = exp2f(s[nj][r] - m_run);
    float a0 = (s[0][0]+s[0][1]) + (s[0][2]+s[0][3]);
    float a1 = (s[1][0]+s[1][1]) + (s[1][2]+s[1][3]);
    float a2 = (s[2][0]+s[2][1]) + (s[2][2]+s[2][3]);
    float a3 = (s[3][0]+s[3][1]) + (s[3][2]+s[3][3]);
    float rs = (a0+a1) + (a2+a3);
    rs += __shfl_xor(rs,16);
    rs += __shfl_xor(rs,32);
    l_run += rs;
    // PV in two 32-kv halves: Ps holds P^T as [q][kv] (B-frag: col=q)
    #pragma unroll
    for (int hh=0; hh<2; hh++){
      #pragma unroll
      for (int nj=hh*2; nj<hh*2+2; nj++){
        *(unsigned*)&Ps[w][r16][(nj&1)*16 + kq*4    ] = cvtpk(s[nj][0], s[nj][1]);
        *(unsigned*)&Ps[w][r16][(nj&1)*16 + kq*4 + 2] = cvtpk(s[nj][2], s[nj][3]);
      }
      v8s pa = *(const v8s*)&Ps[w][r16][kq*8];
      v8s vv[4];
      #pragma unroll
      for (int nj=0;nj<4;nj++)
        vv[nj] = *(const v8s*)&Vb2[cur][nj*16+r16][((hh*4+kq)^rx)*8];
      #pragma unroll
      for (int nj=0;nj<4;nj++)
        o[nj] = MFMA16(vv[nj], pa, o[nj]);   // A=V^T, B=P^T -> O q on lane&15
    }
  }
  float invl = 1.0f / l_run;
  size_t orow = (size_t)(b*S + qrow0 + r16)*D + h*64;
  #pragma unroll
  for (int nj=0;nj<4;nj++){
    v2u pk;
    pk[0] = cvtpk(o[nj][0]*invl, o[nj][1]*invl);
    pk[1] = cvtpk(o[nj][2]*invl, o[nj][3]*invl);
    *(v2u*)(out + orow + nj*16 + kq*4) = pk;
  }
}

// ---------------- launcher ----------------
extern "C" void kernel_launch(void* const* d_in, const int* in_sizes, int n_in,
                              void* d_out, int out_size, void* d_ws, size_t ws_size,
                              hipStream_t stream)
{
  const int D=1024, DFF=2048, BS=4096;
  const float* x      = (const float*)d_in[0];
  const int*   mask   = (const int*)d_in[1];
  const float* alpha1 = (const float*)d_in[2];
  const float* bias1  = (const float*)d_in[3];
  const float* Wq     = (const float*)d_in[4];
  const float* bq     = (const float*)d_in[5];
  const float* Wk     = (const float*)d_in[6];
  const float* bk     = (const float*)d_in[7];
  const float* Wv     = (const float*)d_in[8];
  const float* bv     = (const float*)d_in[9];
  const float* Wo     = (const float*)d_in[10];
  const float* bo     = (const float*)d_in[11];
  const float* alpha2 = (const float*)d_in[12];
  const float* bias2  = (const float*)d_in[13];
  const float* W1     = (const float*)d_in[14];
  const float* b1     = (const float*)d_in[15];
  const float* W2     = (const float*)d_in[16];
  const float* b2     = (const float*)d_in[17];
  float* outp = (float*)d_out;

  char* ws = (char*)d_ws;
  size_t off = 0;
  auto alloc = [&](size_t bytes){ void* p = ws+off; off += (bytes+255)&~(size_t)255; return p; };
  unsigned short* x2b    = (unsigned short*)alloc((size_t)BS*D*2);
  unsigned short* qB     = (unsigned short*)alloc((size_t)BS*D*2);
  unsigned short* kB     = (unsigned short*)alloc((size_t)BS*D*2);
  unsigned short* vB     = (unsigned short*)alloc((size_t)BS*D*2);
  unsigned short* attnB  = (unsigned short*)alloc((size_t)BS*D*2);
  unsigned short* h1     = (unsigned short*)alloc((size_t)BS*DFF*2);
  float*          xres   = (float*)alloc((size_t)BS*D*4);
  unsigned short* wqkvT  = (unsigned short*)alloc((size_t)3*D*D*2);
  unsigned short* woT    = (unsigned short*)alloc((size_t)D*D*2);
  unsigned short* w1T    = (unsigned short*)alloc((size_t)D*DFF*2);
  unsigned short* w2T    = (unsigned short*)alloc((size_t)DFF*D*2);
  unsigned char*  flg    = (unsigned char*)alloc(2048);
  unsigned short* vTb    = x2b;   // alias: x2b dead between gemm_qkv and ln2

  dim3 tb(32,8);
  transpose_f2b<<<dim3(D/32,  D/32 ), tb, 0, stream>>>(Wq, wqkvT,           D, D);
  transpose_f2b<<<dim3(D/32,  D/32 ), tb, 0, stream>>>(Wk, wqkvT + D*D,     D, D);
  transpose_f2b<<<dim3(D/32,  D/32 ), tb, 0, stream>>>(Wv, wqkvT + 2*D*D,   D, D);
  transpose_f2b<<<dim3(D/32,  D/32 ), tb, 0, stream>>>(Wo, woT, D, D);
  transpose_f2b<<<dim3(DFF/32,D/32 ), tb, 0, stream>>>(W1, w1T, D, DFF);
  transpose_f2b<<<dim3(D/32,  DFF/32), tb, 0, stream>>>(W2, w2T, DFF, D);

  mask_flags<<<2048, 256, 0, stream>>>(mask, flg);
  ln_kernel<<<BS, 256, 0, stream>>>(x, alpha1, bias1, x2b);

  gemm_qkv<<<dim3(BS/128, 24), 256, 0, stream>>>(x2b, wqkvT, bq, bk, bv, qB, kB, vB);

  v_transpose<<<1024, 256, 0, stream>>>(vB, vTb);

  attn_kernel<<<1024, 256, 0, stream>>>(qB, kB, vTb, mask, flg, attnB);

  gemm_bt<1><<<dim3(BS/128, D/128), 256, 0, stream>>>(attnB, woT, bo, x, nullptr, xres, BS, D, D);

  ln_kernel<<<BS, 256, 0, stream>>>(xres, alpha2, bias2, x2b);

  gemm_bt<2><<<dim3(BS/128, DFF/128), 256, 0, stream>>>(x2b, w1T, b1, nullptr, h1, nullptr, BS, DFF, D);
  gemm_bt<3><<<dim3(BS/128, D/128), 256, 0, stream>>>(h1, w2T, b2, xres, nullptr, outp, BS, D, DFF);
}

// Round 9
// 259.255 us; speedup vs baseline: 1.6609x; 1.0497x over previous
//
#include <hip/hip_runtime.h>
#include <math.h>

typedef __attribute__((ext_vector_type(8))) short v8s;
typedef __attribute__((ext_vector_type(4))) float v4f;
typedef __attribute__((ext_vector_type(4))) unsigned int v4u;
typedef __attribute__((ext_vector_type(2))) unsigned int v2u;

#define MFMA16(a,b,c) __builtin_amdgcn_mfma_f32_16x16x32_bf16(a,b,c,0,0,0)
#define QSCALE 0.18033688011112042f  /* 0.125 * log2(e) */

typedef const __attribute__((address_space(1))) void* gp1_t;
typedef __attribute__((address_space(3))) void* lp3_t;
__device__ __forceinline__ void gll16(const void* g, void* l){
  __builtin_amdgcn_global_load_lds((gp1_t)g, (lp3_t)l, 16, 0, 0);
}
#define VMCNT(n) asm volatile("s_waitcnt vmcnt(" #n ")" ::: "memory")

__device__ __forceinline__ unsigned short f2b(float f){
  unsigned u = __builtin_bit_cast(unsigned, f);
  u += 0x7FFFu + ((u>>16)&1u);
  return (unsigned short)(u>>16);
}
__device__ __forceinline__ unsigned cvtpk(float lo, float hi){
  unsigned r;
  asm("v_cvt_pk_bf16_f32 %0, %1, %2" : "=v"(r) : "v"(lo), "v"(hi));
  return r;
}
__device__ __forceinline__ float gelu_exact(float x){
  return 0.5f*x*(1.0f + erff(x*0.70710678118654752f));
}

// ---------------- LayerNorm (ddof=1, sd+eps) -> bf16 out ----------------
__global__ __launch_bounds__(256) void ln_kernel(const float* __restrict__ x,
    const float* __restrict__ alpha, const float* __restrict__ bias,
    unsigned short* __restrict__ out)
{
  const int D = 1024;
  int row = blockIdx.x;
  int tid = threadIdx.x;
  const float* xr = x + (size_t)row*D;
  v4f v = ((const v4f*)xr)[tid];
  float s  = v[0]+v[1]+v[2]+v[3];
  float s2 = v[0]*v[0]+v[1]*v[1]+v[2]*v[2]+v[3]*v[3];
  #pragma unroll
  for (int off=1; off<64; off<<=1){ s += __shfl_xor(s, off); s2 += __shfl_xor(s2, off); }
  __shared__ float red[8];
  int w = tid>>6;
  if ((tid&63)==0){ red[w]=s; red[4+w]=s2; }
  __syncthreads();
  s  = red[0]+red[1]+red[2]+red[3];
  s2 = red[4]+red[5]+red[6]+red[7];
  float mu  = s*(1.0f/D);
  float var = (s2 - (float)D*mu*mu)*(1.0f/(D-1));
  float inv = 1.0f/(sqrtf(fmaxf(var,0.0f)) + 1e-6f);
  v4f a  = ((const v4f*)alpha)[tid];
  v4f bi = ((const v4f*)bias)[tid];
  unsigned short o[4];
  #pragma unroll
  for (int i=0;i<4;i++) o[i] = f2b(a[i]*(v[i]-mu)*inv + bi[i]);
  v2u pk; pk[0] = (unsigned)o[0] | ((unsigned)o[1]<<16);
          pk[1] = (unsigned)o[2] | ((unsigned)o[3]<<16);
  ((v2u*)(out + (size_t)row*D))[tid] = pk;
}

// ---------------- f32 [K][N] -> bf16 [N][K] transpose ----------------
__global__ __launch_bounds__(256) void transpose_f2b(const float* __restrict__ in,
    unsigned short* __restrict__ out, int K, int N)
{
  __shared__ float t[32][33];
  int n0 = blockIdx.x*32, k0 = blockIdx.y*32;
  int tx = threadIdx.x, ty = threadIdx.y;
  #pragma unroll
  for (int j=0;j<4;j++) t[ty+8*j][tx] = in[(size_t)(k0+ty+8*j)*N + n0+tx];
  __syncthreads();
  #pragma unroll
  for (int j=0;j<4;j++) out[(size_t)(n0+ty+8*j)*K + k0+tx] = f2b(t[tx][ty+8*j]);
}

// ---------------- mask -> per-(b, 64-qtile, 64-ktile) all-ones flags --------
__global__ __launch_bounds__(256) void mask_flags(const int* __restrict__ mask,
    unsigned char* __restrict__ flags)
{
  const int S = 2048;
  int bid = blockIdx.x;            // b*1024 + qt*32 + kt
  int kt = bid & 31, qt = (bid>>5)&31, b = bid>>10;
  int tid = threadIdx.x;
  const int* mp = mask + (size_t)b*S*S + (size_t)(qt*64)*S + kt*64;
  int ok = 1;
  #pragma unroll
  for (int i=0;i<16;i++){
    int idx = tid + i*256;
    int row = idx>>6, col = idx&63;
    ok &= (mp[(size_t)row*S + col] != 0);
  }
  ok = __all(ok) ? 1 : 0;
  __shared__ int f[4];
  if ((tid&63)==0) f[tid>>6] = ok;
  __syncthreads();
  if (tid==0) flags[bid] = (unsigned char)(f[0]&f[1]&f[2]&f[3]);
}

// ---------------- bf16 V [4096][1024] -> vT [bh=32][dk=64][S=2048] ----------
__global__ __launch_bounds__(256) void v_transpose(const unsigned short* __restrict__ vB,
    unsigned short* __restrict__ vT)
{
  __shared__ unsigned short ts[64][68];
  int tt = blockIdx.x & 31, bh = blockIdx.x >> 5;
  int b = bh >> 4, h = bh & 15;
  int tid = threadIdx.x;
  int row = tid>>3, c8 = (tid&7)*8;
  const unsigned short* src = vB + ((size_t)(b*2048 + tt*64))*1024 + h*64;
  #pragma unroll
  for (int j=0;j<2;j++)
    *(v4u*)&ts[row+32*j][c8] = *(const v4u*)(src + (size_t)(row+32*j)*1024 + c8);
  __syncthreads();
  unsigned short* dst = vT + ((size_t)bh*64)*2048 + (size_t)tt*64;
  #pragma unroll
  for (int j=0;j<2;j++){
    int d = row + 32*j;
    unsigned short tmp[8];
    #pragma unroll
    for (int jj=0;jj<8;jj++) tmp[jj] = ts[c8+jj][d];
    *(v4u*)&dst[(size_t)d*2048 + c8] = *(const v4u*)tmp;
  }
}

// ---------------- fused QKV GEMM (3buf, counted vmcnt) ----------------------
__global__ __launch_bounds__(256) void gemm_qkv(
    const unsigned short* __restrict__ A, const unsigned short* __restrict__ Bt,
    const float* __restrict__ bq, const float* __restrict__ bk, const float* __restrict__ bv,
    unsigned short* __restrict__ qB, unsigned short* __restrict__ kB, unsigned short* __restrict__ vB)
{
  const int K = 1024, N = 1024;
  __shared__ unsigned short As[3][128][32];
  __shared__ unsigned short Bs[3][128][32];
  int m0 = blockIdx.x*128;
  int ny = blockIdx.y;              // 0..23
  int seg = ny>>3;
  int n0g = ny*128;
  int tid = threadIdx.x;
  int w = tid>>6, l = tid&63;
  int wm = (w>>1)*64, wn = (w&1)*64;
  int r16 = l&15, kq = l>>4;
  v4f acc[4][4] = {};
  int t4 = tid>>2, c8 = (tid&3)*8;
  const unsigned short* Ag = A  + (size_t)(m0 + t4)*K + c8;
  const unsigned short* Bg = Bt + (size_t)(n0g + t4)*K + c8;
  auto stageG = [&](int kb, int idx){
    char* a = (char*)&As[idx][0][0] + w*1024;
    char* b = (char*)&Bs[idx][0][0] + w*1024;
    gll16(Ag + kb,                a);
    gll16(Ag + (size_t)64*K + kb, a + 4096);
    gll16(Bg + kb,                b);
    gll16(Bg + (size_t)64*K + kb, b + 4096);
  };
  const int nk = K/32;
  stageG(0, 0); stageG(32, 1);
  for (int i=0; i<nk; i++){
    int cur = i%3;
    if (i+1 < nk) VMCNT(4); else VMCNT(0);
    __builtin_amdgcn_s_barrier();
    if (i+2 < nk) stageG((i+2)*32, (i+2)%3);
    v8s a[4], b[4];
    #pragma unroll
    for (int mi=0;mi<4;mi++) a[mi] = *(const v8s*)&As[cur][wm+mi*16+r16][kq*8];
    #pragma unroll
    for (int ni=0;ni<4;ni++) b[ni] = *(const v8s*)&Bs[cur][wn+ni*16+r16][kq*8];
    #pragma unroll
    for (int mi=0;mi<4;mi++)
      #pragma unroll
      for (int ni=0;ni<4;ni++)
        acc[mi][ni] = MFMA16(a[mi], b[ni], acc[mi][ni]);
  }
  unsigned short* ob = (seg==0) ? qB : (seg==1) ? kB : vB;
  const float*    bp = (seg==0) ? bq : (seg==1) ? bk : bv;
  float sc = (seg==0) ? QSCALE : 1.0f;
  int ncol0 = (ny&7)*128;
  #pragma unroll
  for (int mi=0;mi<4;mi++){
    #pragma unroll
    for (int ni=0;ni<4;ni++){
      int col = ncol0 + wn + ni*16 + r16;
      float bvv = bp[col];
      #pragma unroll
      for (int r=0;r<4;r++){
        int row = m0 + wm + mi*16 + kq*4 + r;
        ob[(size_t)row*N + col] = f2b((acc[mi][ni][r] + bvv)*sc);
      }
    }
  }
}

// ---------------- generic 128x128 GEMM (3buf, counted vmcnt) ----------------
// MODE 2: outb = bf16(gelu(acc+bias))
template<int MODE>
__global__ __launch_bounds__(256) void gemm_bt(
    const unsigned short* __restrict__ A, const unsigned short* __restrict__ Bt,
    const float* __restrict__ bias, const float* __restrict__ res,
    unsigned short* __restrict__ outb, float* __restrict__ outf,
    int M, int N, int K)
{
  __shared__ unsigned short As[3][128][32];
  __shared__ unsigned short Bs[3][128][32];
  int m0 = blockIdx.x*128, n0 = blockIdx.y*128;
  int tid = threadIdx.x;
  int w = tid>>6, l = tid&63;
  int wm = (w>>1)*64, wn = (w&1)*64;
  int r16 = l&15, kq = l>>4;
  v4f acc[4][4] = {};
  int t4 = tid>>2, c8 = (tid&3)*8;
  const unsigned short* Ag = A  + (size_t)(m0 + t4)*K + c8;
  const unsigned short* Bg = Bt + (size_t)(n0 + t4)*K + c8;
  auto stageG = [&](int kb, int idx){
    char* a = (char*)&As[idx][0][0] + w*1024;
    char* b = (char*)&Bs[idx][0][0] + w*1024;
    gll16(Ag + kb,                a);
    gll16(Ag + (size_t)64*K + kb, a + 4096);
    gll16(Bg + kb,                b);
    gll16(Bg + (size_t)64*K + kb, b + 4096);
  };
  const int nk = K/32;
  stageG(0, 0); stageG(32, 1);
  for (int i=0; i<nk; i++){
    int cur = i%3;
    if (i+1 < nk) VMCNT(4); else VMCNT(0);
    __builtin_amdgcn_s_barrier();
    if (i+2 < nk) stageG((i+2)*32, (i+2)%3);
    v8s a[4], b[4];
    #pragma unroll
    for (int mi=0;mi<4;mi++) a[mi] = *(const v8s*)&As[cur][wm+mi*16+r16][kq*8];
    #pragma unroll
    for (int ni=0;ni<4;ni++) b[ni] = *(const v8s*)&Bs[cur][wn+ni*16+r16][kq*8];
    #pragma unroll
    for (int mi=0;mi<4;mi++)
      #pragma unroll
      for (int ni=0;ni<4;ni++)
        acc[mi][ni] = MFMA16(a[mi], b[ni], acc[mi][ni]);
  }
  #pragma unroll
  for (int mi=0;mi<4;mi++){
    #pragma unroll
    for (int ni=0;ni<4;ni++){
      int col = n0 + wn + ni*16 + r16;
      float bv = bias[col];
      #pragma unroll
      for (int r=0;r<4;r++){
        int row = m0 + wm + mi*16 + kq*4 + r;
        float t = acc[mi][ni][r] + bv;
        if (MODE==2) t = gelu_exact(t);
        if (MODE==2) outb[(size_t)row*N + col] = f2b(t);
        else         outf[(size_t)row*N + col] = t + res[(size_t)row*N + col];
      }
    }
  }
}

// ---------------- 64x128 GEMM (3buf, counted vmcnt), 2 blocks/CU grids ------
// MODE 1: outf = acc+bias+res ; MODE 3: outf = gelu(acc+bias)+res
template<int MODE>
__global__ __launch_bounds__(256) void gemm64_bt(
    const unsigned short* __restrict__ A, const unsigned short* __restrict__ Bt,
    const float* __restrict__ bias, const float* __restrict__ res,
    float* __restrict__ outf, int M, int N, int K)
{
  __shared__ unsigned short As[3][64][32];
  __shared__ unsigned short Bs[3][128][32];
  int m0 = blockIdx.x*64, n0 = blockIdx.y*128;
  int tid = threadIdx.x;
  int w = tid>>6, l = tid&63;
  int wm = (w>>1)*32, wn = (w&1)*64;
  int r16 = l&15, kq = l>>4;
  v4f acc[2][4] = {};
  int t4 = tid>>2, c8 = (tid&3)*8;
  const unsigned short* Ag = A  + (size_t)(m0 + t4)*K + c8;
  const unsigned short* Bg = Bt + (size_t)(n0 + t4)*K + c8;
  auto stageG = [&](int kb, int idx){
    char* a = (char*)&As[idx][0][0] + w*1024;
    char* b = (char*)&Bs[idx][0][0] + w*1024;
    gll16(Ag + kb,                a);
    gll16(Bg + kb,                b);
    gll16(Bg + (size_t)64*K + kb, b + 4096);
  };
  const int nk = K/32;
  stageG(0, 0); stageG(32, 1);
  for (int i=0; i<nk; i++){
    int cur = i%3;
    if (i+1 < nk) VMCNT(3); else VMCNT(0);
    __builtin_amdgcn_s_barrier();
    if (i+2 < nk) stageG((i+2)*32, (i+2)%3);
    v8s a[2], b[4];
    #pragma unroll
    for (int mi=0;mi<2;mi++) a[mi] = *(const v8s*)&As[cur][wm+mi*16+r16][kq*8];
    #pragma unroll
    for (int ni=0;ni<4;ni++) b[ni] = *(const v8s*)&Bs[cur][wn+ni*16+r16][kq*8];
    #pragma unroll
    for (int mi=0;mi<2;mi++)
      #pragma unroll
      for (int ni=0;ni<4;ni++)
        acc[mi][ni] = MFMA16(a[mi], b[ni], acc[mi][ni]);
  }
  #pragma unroll
  for (int mi=0;mi<2;mi++){
    #pragma unroll
    for (int ni=0;ni<4;ni++){
      int col = n0 + wn + ni*16 + r16;
      float bv = bias[col];
      #pragma unroll
      for (int r=0;r<4;r++){
        int row = m0 + wm + mi*16 + kq*4 + r;
        float t = acc[mi][ni][r] + bv;
        if (MODE==3) t = gelu_exact(t);
        outf[(size_t)row*N + col] = t + res[(size_t)row*N + col];
      }
    }
  }
}

// ---------------- flash attention: 8 waves, 3buf, counted vmcnt -------------
// block = (b,h,128 q-rows) XCD-swizzled; 8 waves x 16 q-rows.
__global__ __launch_bounds__(512, 4) void attn_kernel(
    const unsigned short* __restrict__ Q, const unsigned short* __restrict__ Kb,
    const unsigned short* __restrict__ vT, const int* __restrict__ mask,
    const unsigned char* __restrict__ flags, unsigned short* __restrict__ out)
{
  const int S = 2048, D = 1024;
  __shared__ unsigned short Kb3[3][64][64];  // 24 KB
  __shared__ unsigned short Vb3[3][64][64];  // 24 KB
  __shared__ unsigned short Ps[8][16][36];   // 9 KB
  int bid = (blockIdx.x & 7)*64 + (blockIdx.x >> 3);   // 512 blocks, bijective
  int qt = bid & 15;            // 128-row q tile
  int bh = bid >> 4;
  int b = bh >> 4, h = bh & 15;
  int tid = threadIdx.x, w = tid>>6, l = tid&63;
  int r16 = l&15, kq = l>>4;
  const unsigned short* Qp  = Q  + (size_t)b*S*D + h*64;
  const unsigned short* Kp  = Kb + (size_t)b*S*D + h*64;
  const unsigned short* vTp = vT + (size_t)bh*64*S;
  int qrow0 = qt*128 + w*16;
  v8s qf[2];
  #pragma unroll
  for (int ks=0;ks<2;ks++)
    qf[ks] = *(const v8s*)(Qp + (size_t)(qrow0+r16)*D + ks*32 + kq*8);
  float m_run = -1e30f, l_run = 0.0f;
  v4f o[4] = {};
  const int* mp = mask + (size_t)b*S*S;
  const unsigned char* fl = flags + ((size_t)b*32 + qt*2)*32;

  int srow = l>>3;
  int gsw  = (l&7) ^ srow;       // pre-swizzled source granule (rule #21)
  auto stage = [&](int kt, int idx){
    int kt64 = kt*64;
    int row = w*8 + srow;        // 8 waves cover 64 rows
    gll16(Kp  + (size_t)(kt64+row)*D + gsw*8, &Kb3[idx][w*8][0]);
    gll16(vTp + (size_t)row*S + kt64 + gsw*8, &Vb3[idx][w*8][0]);
  };

  stage(0, 0); stage(1, 1);
  for (int kt=0; kt<32; kt++){
    int cur = kt%3;
    if (kt+1 < 32) VMCNT(2); else VMCNT(0);
    __builtin_amdgcn_s_barrier();
    if (kt+2 < 32) stage(kt+2, (kt+2)%3);
    int kt64 = kt*64;
    int rx = r16 & 7;
    // swapped QK^T: s[nj][r] = P^T[kv = kt64+nj*16+kq*4+r][q = r16]
    v4f s[4] = {};
    #pragma unroll
    for (int ks=0; ks<2; ks++){
      v8s kf[4];
      #pragma unroll
      for (int nj=0; nj<4; nj++)
        kf[nj] = *(const v8s*)&Kb3[cur][nj*16+r16][((ks*4+kq)^rx)*8];
      #pragma unroll
      for (int nj=0; nj<4; nj++)
        s[nj] = MFMA16(kf[nj], qf[ks], s[nj]);   // A=K, B=Q
    }
    // mask slow path (skipped for all-ones tiles)
    if (!(fl[kt] & fl[32+kt])){
      int qrow = qrow0 + r16;
      #pragma unroll
      for (int nj=0;nj<4;nj++){
        #pragma unroll
        for (int r=0;r<4;r++){
          int kcol = kt64 + nj*16 + kq*4 + r;
          if (mp[(size_t)qrow*S + kcol] == 0) s[nj][r] = -3.0e38f;
        }
      }
    }
    // lane-local online softmax (exp2 domain), defer-max
    float t0 = fmaxf(fmaxf(s[0][0],s[0][1]), fmaxf(s[0][2],s[0][3]));
    float t1 = fmaxf(fmaxf(s[1][0],s[1][1]), fmaxf(s[1][2],s[1][3]));
    float t2 = fmaxf(fmaxf(s[2][0],s[2][1]), fmaxf(s[2][2],s[2][3]));
    float t3 = fmaxf(fmaxf(s[3][0],s[3][1]), fmaxf(s[3][2],s[3][3]));
    float tm = fmaxf(fmaxf(t0,t1), fmaxf(t2,t3));
    tm = fmaxf(tm, __shfl_xor(tm,16));
    tm = fmaxf(tm, __shfl_xor(tm,32));
    if (!__all(tm <= m_run + 11.5f)){
      float mn = fmaxf(m_run, tm);
      float corr = exp2f(m_run - mn);
      m_run = mn;
      l_run *= corr;
      #pragma unroll
      for (int nj=0;nj<4;nj++)
        #pragma unroll
        for (int r=0;r<4;r++) o[nj][r] *= corr;
    }
    #pragma unroll
    for (int nj=0;nj<4;nj++)
      #pragma unroll
      for (int r=0;r<4;r++)
        s[nj][r] = exp2f(s[nj][r] - m_run);
    float a0 = (s[0][0]+s[0][1]) + (s[0][2]+s[0][3]);
    float a1 = (s[1][0]+s[1][1]) + (s[1][2]+s[1][3]);
    float a2 = (s[2][0]+s[2][1]) + (s[2][2]+s[2][3]);
    float a3 = (s[3][0]+s[3][1]) + (s[3][2]+s[3][3]);
    float rs = (a0+a1) + (a2+a3);
    rs += __shfl_xor(rs,16);
    rs += __shfl_xor(rs,32);
    l_run += rs;
    // PV in two 32-kv halves: Ps holds P^T as [q][kv]
    #pragma unroll
    for (int hh=0; hh<2; hh++){
      #pragma unroll
      for (int nj=hh*2; nj<hh*2+2; nj++){
        *(unsigned*)&Ps[w][r16][(nj&1)*16 + kq*4    ] = cvtpk(s[nj][0], s[nj][1]);
        *(unsigned*)&Ps[w][r16][(nj&1)*16 + kq*4 + 2] = cvtpk(s[nj][2], s[nj][3]);
      }
      v8s pa = *(const v8s*)&Ps[w][r16][kq*8];
      v8s vv[4];
      #pragma unroll
      for (int nj=0;nj<4;nj++)
        vv[nj] = *(const v8s*)&Vb3[cur][nj*16+r16][((hh*4+kq)^rx)*8];
      #pragma unroll
      for (int nj=0;nj<4;nj++)
        o[nj] = MFMA16(vv[nj], pa, o[nj]);   // A=V^T, B=P^T
    }
  }
  float invl = 1.0f / l_run;
  size_t orow = (size_t)(b*S + qrow0 + r16)*D + h*64;
  #pragma unroll
  for (int nj=0;nj<4;nj++){
    v2u pk;
    pk[0] = cvtpk(o[nj][0]*invl, o[nj][1]*invl);
    pk[1] = cvtpk(o[nj][2]*invl, o[nj][3]*invl);
    *(v2u*)(out + orow + nj*16 + kq*4) = pk;
  }
}

// ---------------- launcher ----------------
extern "C" void kernel_launch(void* const* d_in, const int* in_sizes, int n_in,
                              void* d_out, int out_size, void* d_ws, size_t ws_size,
                              hipStream_t stream)
{
  const int D=1024, DFF=2048, BS=4096;
  const float* x      = (const float*)d_in[0];
  const int*   mask   = (const int*)d_in[1];
  const float* alpha1 = (const float*)d_in[2];
  const float* bias1  = (const float*)d_in[3];
  const float* Wq     = (const float*)d_in[4];
  const float* bq     = (const float*)d_in[5];
  const float* Wk     = (const float*)d_in[6];
  const float* bk     = (const float*)d_in[7];
  const float* Wv     = (const float*)d_in[8];
  const float* bv     = (const float*)d_in[9];
  const float* Wo     = (const float*)d_in[10];
  const float* bo     = (const float*)d_in[11];
  const float* alpha2 = (const float*)d_in[12];
  const float* bias2  = (const float*)d_in[13];
  const float* W1     = (const float*)d_in[14];
  const float* b1     = (const float*)d_in[15];
  const float* W2     = (const float*)d_in[16];
  const float* b2     = (const float*)d_in[17];
  float* outp = (float*)d_out;

  char* ws = (char*)d_ws;
  size_t off = 0;
  auto alloc = [&](size_t bytes){ void* p = ws+off; off += (bytes+255)&~(size_t)255; return p; };
  unsigned short* x2b    = (unsigned short*)alloc((size_t)BS*D*2);
  unsigned short* qB     = (unsigned short*)alloc((size_t)BS*D*2);
  unsigned short* kB     = (unsigned short*)alloc((size_t)BS*D*2);
  unsigned short* vB     = (unsigned short*)alloc((size_t)BS*D*2);
  unsigned short* attnB  = (unsigned short*)alloc((size_t)BS*D*2);
  unsigned short* h1     = (unsigned short*)alloc((size_t)BS*DFF*2);
  float*          xres   = (float*)alloc((size_t)BS*D*4);
  unsigned short* wqkvT  = (unsigned short*)alloc((size_t)3*D*D*2);
  unsigned short* woT    = (unsigned short*)alloc((size_t)D*D*2);
  unsigned short* w1T    = (unsigned short*)alloc((size_t)D*DFF*2);
  unsigned short* w2T    = (unsigned short*)alloc((size_t)DFF*D*2);
  unsigned char*  flg    = (unsigned char*)alloc(2048);
  unsigned short* vTb    = x2b;   // alias: x2b dead between gemm_qkv and ln2

  dim3 tb(32,8);
  transpose_f2b<<<dim3(D/32,  D/32 ), tb, 0, stream>>>(Wq, wqkvT,           D, D);
  transpose_f2b<<<dim3(D/32,  D/32 ), tb, 0, stream>>>(Wk, wqkvT + D*D,     D, D);
  transpose_f2b<<<dim3(D/32,  D/32 ), tb, 0, stream>>>(Wv, wqkvT + 2*D*D,   D, D);
  transpose_f2b<<<dim3(D/32,  D/32 ), tb, 0, stream>>>(Wo, woT, D, D);
  transpose_f2b<<<dim3(DFF/32,D/32 ), tb, 0, stream>>>(W1, w1T, D, DFF);
  transpose_f2b<<<dim3(D/32,  DFF/32), tb, 0, stream>>>(W2, w2T, DFF, D);

  mask_flags<<<2048, 256, 0, stream>>>(mask, flg);
  ln_kernel<<<BS, 256, 0, stream>>>(x, alpha1, bias1, x2b);

  gemm_qkv<<<dim3(BS/128, 24), 256, 0, stream>>>(x2b, wqkvT, bq, bk, bv, qB, kB, vB);

  v_transpose<<<1024, 256, 0, stream>>>(vB, vTb);

  attn_kernel<<<512, 512, 0, stream>>>(qB, kB, vTb, mask, flg, attnB);

  gemm64_bt<1><<<dim3(BS/64, D/128), 256, 0, stream>>>(attnB, woT, bo, x, xres, BS, D, D);

  ln_kernel<<<BS, 256, 0, stream>>>(xres, alpha2, bias2, x2b);

  gemm_bt<2><<<dim3(BS/128, DFF/128), 256, 0, stream>>>(x2b, w1T, b1, nullptr, h1, nullptr, BS, DFF, D);
  gemm64_bt<3><<<dim3(BS/64, D/128), 256, 0, stream>>>(h1, w2T, b2, xres, outp, BS, D, DFF);
}